// Round 1
// baseline (932.023 us; speedup 1.0000x reference)
//
#include <hip/hip_runtime.h>

#define D 64

__device__ __forceinline__ float bcast(float v, int l) {
    return __uint_as_float(__builtin_amdgcn_readlane(__float_as_uint(v), l));
}

// One wave per edge: lane j moves x[src][j] -> atomicAdd agg[dst][j].
// Lane 0 also bumps deg[dst] (first pass only).
__global__ void __launch_bounds__(256) scatter_kernel(
    const float* __restrict__ x,      // [n, 64]
    const int*   __restrict__ src,    // [E]
    const int*   __restrict__ dst,    // [E]
    float*       __restrict__ agg,    // [n, 64] pre-zeroed
    float*       __restrict__ deg,    // [n] pre-zeroed, or nullptr
    int nedges)
{
    int lane = threadIdx.x & 63;
    int wid  = (blockIdx.x * blockDim.x + threadIdx.x) >> 6;
    int nw   = (gridDim.x * blockDim.x) >> 6;
    for (int e = wid; e < nedges; e += nw) {
        int s = src[e];
        int d = dst[e];
        float v = x[(size_t)s * D + lane];
        atomicAdd(&agg[(size_t)d * D + lane], v);
        if (deg != nullptr && lane == 0) atomicAdd(&deg[d], 1.0f);
    }
}

// out[node][j] = act( b[j] + sum_k x[node][k]*W[j][k] + sum_k (agg[node][k]/deg)*W[j][64+k] )
// One wave per node; lane j owns output j. W staged transposed in LDS as
// float4 packs of 4 consecutive k per lane -> ds_read_b128, conflict-free.
template <bool RELU>
__global__ void __launch_bounds__(256) lin_kernel(
    const float* __restrict__ x,    // [n, 64] self features
    const float* __restrict__ agg,  // [n, 64] neighbor sums
    const float* __restrict__ deg,  // [n]
    const float* __restrict__ W,    // [64, 128] row-major
    const float* __restrict__ b,    // [64]
    float*       __restrict__ out,  // [n, 64]
    int n)
{
    __shared__ float4 Wt4[32 * 64];   // Wt4[k4*64 + j] = W[j][4k4..4k4+3]
    __shared__ float  bs[64];
    float* Wt = (float*)Wt4;
    for (int i = threadIdx.x; i < 64 * 128; i += blockDim.x) {
        int j = i >> 7, k = i & 127;
        Wt[(k >> 2) * 256 + j * 4 + (k & 3)] = W[i];
    }
    if (threadIdx.x < 64) bs[threadIdx.x] = b[threadIdx.x];
    __syncthreads();

    int lane = threadIdx.x & 63;
    int wid  = (blockIdx.x * blockDim.x + threadIdx.x) >> 6;
    int nw   = (gridDim.x * blockDim.x) >> 6;
    for (int node = wid; node < n; node += nw) {
        float xv = x[(size_t)node * D + lane];
        float dg = fmaxf(deg[node], 1.0f);
        float av = agg[(size_t)node * D + lane] / dg;
        float sum = bs[lane];
        #pragma unroll
        for (int k4 = 0; k4 < 16; ++k4) {   // self half: k = 0..63
            float4 w = Wt4[k4 * 64 + lane];
            sum = fmaf(bcast(xv, 4 * k4 + 0), w.x, sum);
            sum = fmaf(bcast(xv, 4 * k4 + 1), w.y, sum);
            sum = fmaf(bcast(xv, 4 * k4 + 2), w.z, sum);
            sum = fmaf(bcast(xv, 4 * k4 + 3), w.w, sum);
        }
        #pragma unroll
        for (int k4 = 16; k4 < 32; ++k4) {  // neighbor half: k = 64..127
            float4 w = Wt4[k4 * 64 + lane];
            int kk = 4 * (k4 - 16);
            sum = fmaf(bcast(av, kk + 0), w.x, sum);
            sum = fmaf(bcast(av, kk + 1), w.y, sum);
            sum = fmaf(bcast(av, kk + 2), w.z, sum);
            sum = fmaf(bcast(av, kk + 3), w.w, sum);
        }
        out[(size_t)node * D + lane] = RELU ? fmaxf(sum, 0.0f) : sum;
    }
}

// Classifier head: h = relu(x2 @ Wc1^T + bc1); logits = h @ Wc2^T + bc2.
// Thread per node; weights in LDS (uniform broadcast reads).
__global__ void __launch_bounds__(256) head_kernel(
    const float* __restrict__ x2,   // [n, 64]
    const float* __restrict__ Wc1,  // [32, 64]
    const float* __restrict__ bc1,  // [32]
    const float* __restrict__ Wc2,  // [2, 32]
    const float* __restrict__ bc2,  // [2]
    float*       __restrict__ out,  // [n, 2]
    int n)
{
    __shared__ float w1[32 * 64];
    __shared__ float b1s[32];
    __shared__ float w2[64];
    __shared__ float b2s[2];
    for (int i = threadIdx.x; i < 32 * 64; i += blockDim.x) w1[i] = Wc1[i];
    if (threadIdx.x < 32) b1s[threadIdx.x] = bc1[threadIdx.x];
    if (threadIdx.x < 64) w2[threadIdx.x] = Wc2[threadIdx.x];
    if (threadIdx.x < 2)  b2s[threadIdx.x] = bc2[threadIdx.x];
    __syncthreads();

    int t0     = blockIdx.x * blockDim.x + threadIdx.x;
    int stride = gridDim.x * blockDim.x;
    for (int node = t0; node < n; node += stride) {
        float xr[64];
        const float4* xp = (const float4*)(x2 + (size_t)node * D);
        #pragma unroll
        for (int q = 0; q < 16; ++q) {
            float4 v = xp[q];
            xr[4*q+0] = v.x; xr[4*q+1] = v.y; xr[4*q+2] = v.z; xr[4*q+3] = v.w;
        }
        float l0 = b2s[0], l1 = b2s[1];
        for (int j = 0; j < 32; ++j) {
            float h = b1s[j];
            #pragma unroll
            for (int k = 0; k < 64; ++k) h = fmaf(xr[k], w1[j * 64 + k], h);
            h = fmaxf(h, 0.0f);
            l0 = fmaf(h, w2[j], l0);
            l1 = fmaf(h, w2[32 + j], l1);
        }
        out[(size_t)node * 2 + 0] = l0;
        out[(size_t)node * 2 + 1] = l1;
    }
}

extern "C" void kernel_launch(void* const* d_in, const int* in_sizes, int n_in,
                              void* d_out, int out_size, void* d_ws, size_t ws_size,
                              hipStream_t stream)
{
    const float* feat = (const float*)d_in[0];
    const int*   eidx = (const int*)d_in[1];
    const float* W1   = (const float*)d_in[2];
    const float* b1   = (const float*)d_in[3];
    const float* W2   = (const float*)d_in[4];
    const float* b2   = (const float*)d_in[5];
    const float* Wc1  = (const float*)d_in[6];
    const float* bc1  = (const float*)d_in[7];
    const float* Wc2  = (const float*)d_in[8];
    const float* bc2  = (const float*)d_in[9];

    int n = in_sizes[0] / D;         // 100000
    int E = in_sizes[1] / 2;         // 1600000
    const int* src = eidx;           // edge_index[0]
    const int* dst = eidx + E;       // edge_index[1]

    float* agg = (float*)d_ws;                     // [n*64]
    float* x1  = agg + (size_t)n * D;              // [n*64]
    float* deg = x1 + (size_t)n * D;               // [n]

    // Layer 1
    hipMemsetAsync(agg, 0, (size_t)n * D * sizeof(float), stream);
    hipMemsetAsync(deg, 0, (size_t)n * sizeof(float), stream);
    scatter_kernel<<<2048, 256, 0, stream>>>(feat, src, dst, agg, deg, E);
    lin_kernel<true><<<1024, 256, 0, stream>>>(feat, agg, deg, W1, b1, x1, n);

    // Layer 2 (x2 written in-place over agg: per-node read-then-write, disjoint rows)
    hipMemsetAsync(agg, 0, (size_t)n * D * sizeof(float), stream);
    scatter_kernel<<<2048, 256, 0, stream>>>(x1, src, dst, agg, nullptr, E);
    lin_kernel<true><<<1024, 256, 0, stream>>>(x1, agg, deg, W2, b2, agg, n);

    // Head
    head_kernel<<<391, 256, 0, stream>>>(agg, Wc1, bc1, Wc2, bc2, (float*)d_out, n);
}